// Round 1
// baseline (1358.564 us; speedup 1.0000x reference)
//
#include <hip/hip_runtime.h>
#include <cstdint>
#include <cstddef>

#define NNODES 50000
#define DIM 128
#define K5 640          // 5*DIM
#define OUTD 128
#define MPAD 50048      // NNODES rounded up to multiple of 64
#define EPS_STD 1e-5f
#define EPS_BN 1e-5f
#define LDA 40          // padded LDS leading dim (breaks 8-way bank conflict at 32)
#define LDB 40

typedef __attribute__((ext_vector_type(8))) __bf16 bf16x8;
typedef __attribute__((ext_vector_type(4))) float f32x4;

__device__ __forceinline__ unsigned short f2bf(float f) {
  // round-to-nearest-even fp32 -> bf16
  unsigned int u = __float_as_uint(f);
  u = u + 0x7fffu + ((u >> 16) & 1u);
  return (unsigned short)(u >> 16);
}

// ---------------- histogram ----------------
__global__ void hist_k(const int* __restrict__ idx, int* __restrict__ counts, int E) {
  int e = blockIdx.x * 256 + threadIdx.x;
  if (e < E) atomicAdd(&counts[idx[e]], 1);
}

// ---------------- 2-level exclusive scan ----------------
__global__ void scan1_k(const int* __restrict__ counts, int* __restrict__ offsets,
                        int* __restrict__ blocksums, int n) {
  __shared__ int sh[256];
  int t = threadIdx.x;
  int i = blockIdx.x * 256 + t;
  int v = (i < n) ? counts[i] : 0;
  sh[t] = v; __syncthreads();
  for (int off = 1; off < 256; off <<= 1) {
    int add = (t >= off) ? sh[t - off] : 0;
    __syncthreads();
    sh[t] += add;
    __syncthreads();
  }
  if (i < n) offsets[i] = sh[t] - v;   // exclusive
  if (t == 255) blocksums[blockIdx.x] = sh[t];
}

__global__ void scan2_k(int* __restrict__ blocksums, int nb) {
  __shared__ int sh[256];
  int t = threadIdx.x;
  int v = (t < nb) ? blocksums[t] : 0;
  sh[t] = v; __syncthreads();
  for (int off = 1; off < 256; off <<= 1) {
    int add = (t >= off) ? sh[t - off] : 0;
    __syncthreads();
    sh[t] += add;
    __syncthreads();
  }
  if (t < nb) blocksums[t] = sh[t] - v; // exclusive
}

__global__ void scan3_k(int* __restrict__ offsets, const int* __restrict__ blocksums,
                        int* __restrict__ cursor, int n) {
  int i = blockIdx.x * 256 + threadIdx.x;
  if (i < n) {
    int o = offsets[i] + blocksums[blockIdx.x];
    offsets[i] = o;
    cursor[i] = o;
  }
}

// ---------------- scatter: counting sort of edge ids ----------------
__global__ void scatter_k(const int* __restrict__ idx, int* __restrict__ cursor,
                          int* __restrict__ sorted, int E) {
  int e = blockIdx.x * 256 + threadIdx.x;
  if (e < E) {
    int p = atomicAdd(&cursor[idx[e]], 1);
    sorted[p] = e;
  }
}

// ---------------- W (fp32 [K5,OUTD]) -> Wt bf16 col-major [OUTD][K5] ----------------
__global__ void convW_k(const float* __restrict__ W, unsigned short* __restrict__ Wt) {
  int t = blockIdx.x * 256 + threadIdx.x;
  if (t >= OUTD * K5) return;
  int c = t / K5, k = t % K5;
  Wt[t] = f2bf(W[(size_t)k * OUTD + c]);
}

// ---------------- per-node aggregation: one wave per node ----------------
__global__ __launch_bounds__(256) void agg_k(
    const float* __restrict__ inp, const int* __restrict__ sorted,
    const int* __restrict__ offsets, const int* __restrict__ counts,
    const float* __restrict__ deg_emb, unsigned short* __restrict__ x) {
  const int wid  = threadIdx.x >> 6;
  const int node = blockIdx.x * 4 + wid;
  const int lane = threadIdx.x & 63;
  const int half = lane >> 5;      // lanes 0-31 do even rows, 32-63 odd rows
  const int sl   = lane & 31;
  const int c0   = sl * 4;         // 4 columns per lane
  unsigned short* xrow = x + (size_t)node * K5;

  if (node >= NNODES) {            // pad rows -> zeros so GEMM can read them
    if (half == 0) {
      ushort4 z = {0, 0, 0, 0};
      #pragma unroll
      for (int sgm = 0; sgm < 5; sgm++) *(ushort4*)(xrow + sgm * DIM + c0) = z;
    }
    return;
  }

  const int start = offsets[node];
  const int cnt   = counts[node];
  float s[4] = {0.f, 0.f, 0.f, 0.f}, q[4] = {0.f, 0.f, 0.f, 0.f};
  float mn[4], mx[4];
  #pragma unroll
  for (int i = 0; i < 4; i++) { mn[i] = INFINITY; mx[i] = -INFINITY; }

  for (int j0 = 0; j0 < cnt; j0 += 64) {
    const int lim = min(64, cnt - j0);
    int myid = 0;
    if (j0 + lane < cnt) myid = sorted[start + j0 + lane];  // coalesced id batch
    for (int j = 0; j < lim; j += 2) {
      const int r = j + half;
      const int e = __shfl(myid, r);
      if (r < lim) {
        const float4 v4 = *(const float4*)(inp + (size_t)e * DIM + c0);
        const float v[4] = {v4.x, v4.y, v4.z, v4.w};
        #pragma unroll
        for (int i = 0; i < 4; i++) {
          s[i] += v[i];
          q[i] += v[i] * v[i];
          mn[i] = fminf(mn[i], v[i]);
          mx[i] = fmaxf(mx[i], v[i]);
        }
      }
    }
  }
  // combine the two half-wave row groups
  #pragma unroll
  for (int i = 0; i < 4; i++) {
    s[i] += __shfl_xor(s[i], 32);
    q[i] += __shfl_xor(q[i], 32);
    mn[i] = fminf(mn[i], __shfl_xor(mn[i], 32));
    mx[i] = fmaxf(mx[i], __shfl_xor(mx[i], 32));
  }
  if (half) return;

  const float inv = 1.0f / (float)max(cnt, 1);
  const int deg = min(cnt, 99);
  const float4 e4 = *(const float4*)(deg_emb + (size_t)deg * DIM + c0);
  const float emb[4] = {e4.x, e4.y, e4.z, e4.w};
  float mean[4], sd[4];
  #pragma unroll
  for (int i = 0; i < 4; i++) {
    mean[i] = s[i] * inv;
    float var = q[i] * inv - mean[i] * mean[i];
    sd[i] = sqrtf(fmaxf(var, 0.f) + EPS_STD);
    if (cnt == 0) { mn[i] = 0.f; mx[i] = 0.f; }  // torch_scatter empty-segment semantics
  }
  { ushort4 u = {f2bf(mean[0]), f2bf(mean[1]), f2bf(mean[2]), f2bf(mean[3])};
    *(ushort4*)(xrow + 0 * DIM + c0) = u; }
  { ushort4 u = {f2bf(mn[0]), f2bf(mn[1]), f2bf(mn[2]), f2bf(mn[3])};
    *(ushort4*)(xrow + 1 * DIM + c0) = u; }
  { ushort4 u = {f2bf(mx[0]), f2bf(mx[1]), f2bf(mx[2]), f2bf(mx[3])};
    *(ushort4*)(xrow + 2 * DIM + c0) = u; }
  { ushort4 u = {f2bf(sd[0]), f2bf(sd[1]), f2bf(sd[2]), f2bf(sd[3])};
    *(ushort4*)(xrow + 3 * DIM + c0) = u; }
  { ushort4 u = {f2bf(emb[0]), f2bf(emb[1]), f2bf(emb[2]), f2bf(emb[3])};
    *(ushort4*)(xrow + 4 * DIM + c0) = u; }
}

// ---------------- GEMM: h[M,128] = x[M,640] @ W[640,128], bf16 MFMA ----------------
__global__ __launch_bounds__(256) void gemm_k(const unsigned short* __restrict__ x,
                                              const unsigned short* __restrict__ Wt,
                                              float* __restrict__ h) {
  __shared__ unsigned short As[64 * LDA];   // 64 rows x 32 k (padded)
  __shared__ unsigned short Bs[128 * LDB];  // 128 cols x 32 k (padded, col-major)
  const int t = threadIdx.x;
  const int m0 = blockIdx.x * 64;
  const int w = t >> 6, lane = t & 63;
  const int lm = lane & 15, lq = lane >> 4;

  f32x4 acc[8];
  #pragma unroll
  for (int i = 0; i < 8; i++) acc[i] = (f32x4){0.f, 0.f, 0.f, 0.f};

  const int arow = t >> 2, akoff = (t & 3) * 8;
  const int bt0 = t * 8, bt1 = 2048 + t * 8;
  const int bc0 = bt0 >> 5, bk0 = bt0 & 31;
  const int bc1 = bt1 >> 5, bk1 = bt1 & 31;

  for (int k0 = 0; k0 < K5; k0 += 32) {
    *(uint4*)&As[arow * LDA + akoff] = *(const uint4*)&x[(size_t)(m0 + arow) * K5 + k0 + akoff];
    *(uint4*)&Bs[bc0 * LDB + bk0]    = *(const uint4*)&Wt[(size_t)bc0 * K5 + k0 + bk0];
    *(uint4*)&Bs[bc1 * LDB + bk1]    = *(const uint4*)&Wt[(size_t)bc1 * K5 + k0 + bk1];
    __syncthreads();
    const bf16x8 a = *(const bf16x8*)&As[(w * 16 + lm) * LDA + lq * 8];
    #pragma unroll
    for (int tt = 0; tt < 8; tt++) {
      const bf16x8 b = *(const bf16x8*)&Bs[(tt * 16 + lm) * LDB + lq * 8];
      acc[tt] = __builtin_amdgcn_mfma_f32_16x16x32_bf16(a, b, acc[tt], 0, 0, 0);
    }
    __syncthreads();
  }
  // D layout: col = lane&15 (within 16-tile), row = (lane>>4)*4 + reg
  #pragma unroll
  for (int tt = 0; tt < 8; tt++) {
    #pragma unroll
    for (int r = 0; r < 4; r++) {
      const int row = m0 + w * 16 + lq * 4 + r;
      if (row < NNODES) h[(size_t)row * OUTD + tt * 16 + lm] = acc[tt][r];
    }
  }
}

// ---------------- batchnorm stats: column sums over rows ----------------
__global__ void stats_k(const float* __restrict__ h, float* __restrict__ colsum,
                        float* __restrict__ colsumsq) {
  const int t = threadIdx.x;
  const int col = t & 127;
  const int rh = t >> 7;
  const int rend = min(blockIdx.x * 128 + 128, NNODES);
  float s = 0.f, q = 0.f;
  for (int r = blockIdx.x * 128 + rh; r < rend; r += 2) {
    const float v = h[(size_t)r * OUTD + col];
    s += v; q += v * v;
  }
  atomicAdd(&colsum[col], s);
  atomicAdd(&colsumsq[col], q);
}

// ---------------- normalize + relu (in place on d_out) ----------------
__global__ void norm_k(float* __restrict__ h, const float* __restrict__ colsum,
                       const float* __restrict__ colsumsq, const float* __restrict__ gamma,
                       const float* __restrict__ beta) {
  const int i = blockIdx.x * 256 + threadIdx.x;   // float4 index
  const int total = NNODES * OUTD / 4;
  if (i >= total) return;
  const int c0 = (i * 4) & (OUTD - 1);
  const float invN = 1.0f / (float)NNODES;
  float4 v = *(const float4*)(h + (size_t)i * 4);
  float out[4] = {v.x, v.y, v.z, v.w};
  #pragma unroll
  for (int j = 0; j < 4; j++) {
    const int c = c0 + j;
    const float mu = colsum[c] * invN;
    const float var = colsumsq[c] * invN - mu * mu;
    const float rs = rsqrtf(var + EPS_BN);
    const float tv = (out[j] - mu) * rs * gamma[c] + beta[c];
    out[j] = fmaxf(tv, 0.f);
  }
  float4 o4 = {out[0], out[1], out[2], out[3]};
  *(float4*)(h + (size_t)i * 4) = o4;
}

extern "C" void kernel_launch(void* const* d_in, const int* in_sizes, int n_in,
                              void* d_out, int out_size, void* d_ws, size_t ws_size,
                              hipStream_t stream) {
  const float* inputs  = (const float*)d_in[0];
  const int*   index   = (const int*)d_in[1];
  const float* deg_emb = (const float*)d_in[2];
  const float* W       = (const float*)d_in[3];
  const float* gamma   = (const float*)d_in[4];
  const float* beta    = (const float*)d_in[5];
  const int E = in_sizes[1];

  char* ws = (char*)d_ws;
  size_t o = 0;
  int* counts = (int*)(ws + o);       o += (size_t)NNODES * 4;
  float* colsum = (float*)(ws + o);   o += 128 * 4;
  float* colsumsq = (float*)(ws + o); o += 128 * 4;
  const size_t zero_bytes = o;        // counts + colsum + colsumsq zeroed together
  o = (o + 255) & ~(size_t)255;
  int* offsets = (int*)(ws + o);      o += (size_t)NNODES * 4;
  o = (o + 255) & ~(size_t)255;
  int* cursor = (int*)(ws + o);       o += (size_t)NNODES * 4;
  o = (o + 255) & ~(size_t)255;
  int* blocksums = (int*)(ws + o);    o += 256 * 4;
  o = (o + 255) & ~(size_t)255;
  int* sorted = (int*)(ws + o);       o += (size_t)E * 4;
  o = (o + 255) & ~(size_t)255;
  unsigned short* Wt = (unsigned short*)(ws + o); o += (size_t)OUTD * K5 * 2;
  o = (o + 255) & ~(size_t)255;
  unsigned short* x = (unsigned short*)(ws + o);  o += (size_t)MPAD * K5 * 2;

  float* h = (float*)d_out;

  hipMemsetAsync(counts, 0, zero_bytes, stream);
  hist_k<<<(E + 255) / 256, 256, 0, stream>>>(index, counts, E);
  const int NB = (NNODES + 255) / 256;
  scan1_k<<<NB, 256, 0, stream>>>(counts, offsets, blocksums, NNODES);
  scan2_k<<<1, 256, 0, stream>>>(blocksums, NB);
  scan3_k<<<NB, 256, 0, stream>>>(offsets, blocksums, cursor, NNODES);
  scatter_k<<<(E + 255) / 256, 256, 0, stream>>>(index, cursor, sorted, E);
  convW_k<<<(OUTD * K5 + 255) / 256, 256, 0, stream>>>(W, Wt);
  agg_k<<<MPAD / 4, 256, 0, stream>>>(inputs, sorted, offsets, counts, deg_emb, x);
  gemm_k<<<MPAD / 64, 256, 0, stream>>>(x, Wt, h);
  stats_k<<<(NNODES + 127) / 128, 256, 0, stream>>>(h, colsum, colsumsq);
  norm_k<<<(NNODES * OUTD / 4 + 255) / 256, 256, 0, stream>>>(h, colsum, colsumsq, gamma, beta);
}

// Round 2
// 1318.592 us; speedup vs baseline: 1.0303x; 1.0303x over previous
//
#include <hip/hip_runtime.h>
#include <cstdint>
#include <cstddef>

#define NNODES 50000
#define DIM 128
#define K5 640          // 5*DIM
#define OUTD 128
#define MPAD 50048      // NNODES rounded up to multiple of 64
#define EPS_STD 1e-5f
#define EPS_BN 1e-5f
#define LDA 40          // padded LDS leading dim (breaks 8-way bank conflict at 32)
#define LDB 40

typedef __attribute__((ext_vector_type(8))) __bf16 bf16x8;
typedef __attribute__((ext_vector_type(4))) float f32x4;

__device__ __forceinline__ unsigned short f2bf(float f) {
  unsigned int u = __float_as_uint(f);
  u = u + 0x7fffu + ((u >> 16) & 1u);
  return (unsigned short)(u >> 16);
}

// ---------------- histogram ----------------
__global__ void hist_k(const int* __restrict__ idx, int* __restrict__ counts, int E) {
  int e = blockIdx.x * 256 + threadIdx.x;
  if (e < E) atomicAdd(&counts[idx[e]], 1);
}

// ---------------- 2-level exclusive scan ----------------
__global__ void scan1_k(const int* __restrict__ counts, int* __restrict__ offsets,
                        int* __restrict__ blocksums, int n) {
  __shared__ int sh[256];
  int t = threadIdx.x;
  int i = blockIdx.x * 256 + t;
  int v = (i < n) ? counts[i] : 0;
  sh[t] = v; __syncthreads();
  for (int off = 1; off < 256; off <<= 1) {
    int add = (t >= off) ? sh[t - off] : 0;
    __syncthreads();
    sh[t] += add;
    __syncthreads();
  }
  if (i < n) offsets[i] = sh[t] - v;   // exclusive
  if (t == 255) blocksums[blockIdx.x] = sh[t];
}

__global__ void scan2_k(int* __restrict__ blocksums, int nb) {
  __shared__ int sh[256];
  int t = threadIdx.x;
  int v = (t < nb) ? blocksums[t] : 0;
  sh[t] = v; __syncthreads();
  for (int off = 1; off < 256; off <<= 1) {
    int add = (t >= off) ? sh[t - off] : 0;
    __syncthreads();
    sh[t] += add;
    __syncthreads();
  }
  if (t < nb) blocksums[t] = sh[t] - v; // exclusive
}

__global__ void scan3_k(int* __restrict__ offsets, const int* __restrict__ blocksums,
                        int* __restrict__ cursor, int n) {
  int i = blockIdx.x * 256 + threadIdx.x;
  if (i < n) {
    int o = offsets[i] + blocksums[blockIdx.x];
    offsets[i] = o;
    cursor[i] = o;
  }
}

// ---------------- scatter: counting sort of edge ids ----------------
__global__ void scatter_k(const int* __restrict__ idx, int* __restrict__ cursor,
                          int* __restrict__ sorted, int E) {
  int e = blockIdx.x * 256 + threadIdx.x;
  if (e < E) {
    int p = atomicAdd(&cursor[idx[e]], 1);
    sorted[p] = e;
  }
}

// ---------------- W (fp32 [K5,OUTD]) -> Wt bf16 col-major [OUTD][K5] ----------------
__global__ void convW_k(const float* __restrict__ W, unsigned short* __restrict__ Wt) {
  int t = blockIdx.x * 256 + threadIdx.x;
  if (t >= OUTD * K5) return;
  int c = t / K5, k = t % K5;
  Wt[t] = f2bf(W[(size_t)k * OUTD + c]);
}

// ---------------- per-node aggregation: one wave per node, 4x MLP ----------------
__global__ __launch_bounds__(256) void agg_k(
    const float* __restrict__ inp, const int* __restrict__ sorted,
    const int* __restrict__ offsets, const int* __restrict__ counts,
    const float* __restrict__ deg_emb, unsigned short* __restrict__ x) {
  const int wid  = threadIdx.x >> 6;
  const int node = blockIdx.x * 4 + wid;
  const int lane = threadIdx.x & 63;
  const int half = lane >> 5;      // lanes 0-31: even rows, 32-63: odd rows
  const int sl   = lane & 31;
  const int c0   = sl * 4;         // 4 columns per lane
  unsigned short* xrow = x + (size_t)node * K5;

  if (node >= NNODES) {            // pad rows -> zeros so GEMM can read them
    if (half == 0) {
      ushort4 z = {0, 0, 0, 0};
      #pragma unroll
      for (int sgm = 0; sgm < 5; sgm++) *(ushort4*)(xrow + sgm * DIM + c0) = z;
    }
    return;
  }

  const int start = offsets[node];
  const int cnt   = counts[node];
  float s[4] = {0.f, 0.f, 0.f, 0.f}, q[4] = {0.f, 0.f, 0.f, 0.f};
  float mn[4], mx[4];
  #pragma unroll
  for (int i = 0; i < 4; i++) { mn[i] = INFINITY; mx[i] = -INFINITY; }

  for (int j0 = 0; j0 < cnt; j0 += 64) {
    const int lim = min(64, cnt - j0);
    int myid = 0;
    if (j0 + lane < cnt) myid = sorted[start + j0 + lane];  // coalesced id batch
    int j = 0;
    // main body: 4 independent row gathers in flight per wave (MLP)
    for (; j + 8 <= lim; j += 8) {
      const int e0 = __shfl(myid, j + 0 + half);
      const int e1 = __shfl(myid, j + 2 + half);
      const int e2 = __shfl(myid, j + 4 + half);
      const int e3 = __shfl(myid, j + 6 + half);
      const float4 a0 = *(const float4*)(inp + (size_t)e0 * DIM + c0);
      const float4 a1 = *(const float4*)(inp + (size_t)e1 * DIM + c0);
      const float4 a2 = *(const float4*)(inp + (size_t)e2 * DIM + c0);
      const float4 a3 = *(const float4*)(inp + (size_t)e3 * DIM + c0);
      const float v0[4] = {a0.x, a0.y, a0.z, a0.w};
      const float v1[4] = {a1.x, a1.y, a1.z, a1.w};
      const float v2[4] = {a2.x, a2.y, a2.z, a2.w};
      const float v3[4] = {a3.x, a3.y, a3.z, a3.w};
      #pragma unroll
      for (int i = 0; i < 4; i++) {
        s[i] += v0[i] + v1[i] + v2[i] + v3[i];
        q[i] += v0[i] * v0[i] + v1[i] * v1[i] + v2[i] * v2[i] + v3[i] * v3[i];
        mn[i] = fminf(fminf(fminf(mn[i], v0[i]), fminf(v1[i], v2[i])), v3[i]);
        mx[i] = fmaxf(fmaxf(fmaxf(mx[i], v0[i]), fmaxf(v1[i], v2[i])), v3[i]);
      }
    }
    // tail
    for (; j < lim; j += 2) {
      const int r = j + half;
      const int e = __shfl(myid, r < lim ? r : (lim - 1));
      if (r < lim) {
        const float4 a = *(const float4*)(inp + (size_t)e * DIM + c0);
        const float v[4] = {a.x, a.y, a.z, a.w};
        #pragma unroll
        for (int i = 0; i < 4; i++) {
          s[i] += v[i];
          q[i] += v[i] * v[i];
          mn[i] = fminf(mn[i], v[i]);
          mx[i] = fmaxf(mx[i], v[i]);
        }
      }
    }
  }
  // combine the two half-wave row groups
  #pragma unroll
  for (int i = 0; i < 4; i++) {
    s[i] += __shfl_xor(s[i], 32);
    q[i] += __shfl_xor(q[i], 32);
    mn[i] = fminf(mn[i], __shfl_xor(mn[i], 32));
    mx[i] = fmaxf(mx[i], __shfl_xor(mx[i], 32));
  }
  if (half) return;

  const float inv = 1.0f / (float)max(cnt, 1);
  const int deg = min(cnt, 99);
  const float4 e4 = *(const float4*)(deg_emb + (size_t)deg * DIM + c0);
  const float emb[4] = {e4.x, e4.y, e4.z, e4.w};
  float mean[4], sd[4];
  #pragma unroll
  for (int i = 0; i < 4; i++) {
    mean[i] = s[i] * inv;
    float var = q[i] * inv - mean[i] * mean[i];
    sd[i] = sqrtf(fmaxf(var, 0.f) + EPS_STD);
    if (cnt == 0) { mn[i] = 0.f; mx[i] = 0.f; }  // torch_scatter empty-segment semantics
  }
  { ushort4 u = {f2bf(mean[0]), f2bf(mean[1]), f2bf(mean[2]), f2bf(mean[3])};
    *(ushort4*)(xrow + 0 * DIM + c0) = u; }
  { ushort4 u = {f2bf(mn[0]), f2bf(mn[1]), f2bf(mn[2]), f2bf(mn[3])};
    *(ushort4*)(xrow + 1 * DIM + c0) = u; }
  { ushort4 u = {f2bf(mx[0]), f2bf(mx[1]), f2bf(mx[2]), f2bf(mx[3])};
    *(ushort4*)(xrow + 2 * DIM + c0) = u; }
  { ushort4 u = {f2bf(sd[0]), f2bf(sd[1]), f2bf(sd[2]), f2bf(sd[3])};
    *(ushort4*)(xrow + 3 * DIM + c0) = u; }
  { ushort4 u = {f2bf(emb[0]), f2bf(emb[1]), f2bf(emb[2]), f2bf(emb[3])};
    *(ushort4*)(xrow + 4 * DIM + c0) = u; }
}

// ---------------- GEMM + fused BN column stats ----------------
__global__ __launch_bounds__(256) void gemm_k(const unsigned short* __restrict__ x,
                                              const unsigned short* __restrict__ Wt,
                                              float* __restrict__ h,
                                              float* __restrict__ colsum,
                                              float* __restrict__ colsumsq) {
  __shared__ unsigned short As[64 * LDA];   // 64 rows x 32 k (padded)
  __shared__ unsigned short Bs[128 * LDB];  // 128 cols x 32 k (padded, col-major)
  __shared__ float sh_s[4 * 128];
  __shared__ float sh_q[4 * 128];
  const int t = threadIdx.x;
  const int m0 = blockIdx.x * 64;
  const int w = t >> 6, lane = t & 63;
  const int lm = lane & 15, lq = lane >> 4;

  f32x4 acc[8];
  #pragma unroll
  for (int i = 0; i < 8; i++) acc[i] = (f32x4){0.f, 0.f, 0.f, 0.f};

  const int arow = t >> 2, akoff = (t & 3) * 8;
  const int bt0 = t * 8, bt1 = 2048 + t * 8;
  const int bc0 = bt0 >> 5, bk0 = bt0 & 31;
  const int bc1 = bt1 >> 5, bk1 = bt1 & 31;

  for (int k0 = 0; k0 < K5; k0 += 32) {
    *(uint4*)&As[arow * LDA + akoff] = *(const uint4*)&x[(size_t)(m0 + arow) * K5 + k0 + akoff];
    *(uint4*)&Bs[bc0 * LDB + bk0]    = *(const uint4*)&Wt[(size_t)bc0 * K5 + k0 + bk0];
    *(uint4*)&Bs[bc1 * LDB + bk1]    = *(const uint4*)&Wt[(size_t)bc1 * K5 + k0 + bk1];
    __syncthreads();
    const bf16x8 a = *(const bf16x8*)&As[(w * 16 + lm) * LDA + lq * 8];
    #pragma unroll
    for (int tt = 0; tt < 8; tt++) {
      const bf16x8 b = *(const bf16x8*)&Bs[(tt * 16 + lm) * LDB + lq * 8];
      acc[tt] = __builtin_amdgcn_mfma_f32_16x16x32_bf16(a, b, acc[tt], 0, 0, 0);
    }
    __syncthreads();
  }
  // D layout: col = lane&15 (within 16-tile), row = (lane>>4)*4 + reg
  float psum[8], psq[8];
  #pragma unroll
  for (int tt = 0; tt < 8; tt++) {
    psum[tt] = 0.f; psq[tt] = 0.f;
    #pragma unroll
    for (int r = 0; r < 4; r++) {
      const int row = m0 + w * 16 + lq * 4 + r;
      if (row < NNODES) {
        const float v = acc[tt][r];
        h[(size_t)row * OUTD + tt * 16 + lm] = v;
        psum[tt] += v;
        psq[tt]  += v * v;
      }
    }
  }
  // wave reduce over lq (lanes lq*16+lm): xor 16, xor 32
  #pragma unroll
  for (int tt = 0; tt < 8; tt++) {
    psum[tt] += __shfl_xor(psum[tt], 16);
    psum[tt] += __shfl_xor(psum[tt], 32);
    psq[tt]  += __shfl_xor(psq[tt], 16);
    psq[tt]  += __shfl_xor(psq[tt], 32);
  }
  if (lq == 0) {
    #pragma unroll
    for (int tt = 0; tt < 8; tt++) {
      sh_s[w * 128 + tt * 16 + lm] = psum[tt];
      sh_q[w * 128 + tt * 16 + lm] = psq[tt];
    }
  }
  __syncthreads();
  if (t < 128) {
    float s = sh_s[t] + sh_s[128 + t] + sh_s[256 + t] + sh_s[384 + t];
    float qv = sh_q[t] + sh_q[128 + t] + sh_q[256 + t] + sh_q[384 + t];
    atomicAdd(&colsum[t], s);
    atomicAdd(&colsumsq[t], qv);
  }
}

// ---------------- normalize + relu (in place on d_out) ----------------
__global__ void norm_k(float* __restrict__ h, const float* __restrict__ colsum,
                       const float* __restrict__ colsumsq, const float* __restrict__ gamma,
                       const float* __restrict__ beta) {
  const int i = blockIdx.x * 256 + threadIdx.x;   // float4 index
  const int total = NNODES * OUTD / 4;
  if (i >= total) return;
  const int c0 = (i * 4) & (OUTD - 1);
  const float invN = 1.0f / (float)NNODES;
  float4 v = *(const float4*)(h + (size_t)i * 4);
  float out[4] = {v.x, v.y, v.z, v.w};
  #pragma unroll
  for (int j = 0; j < 4; j++) {
    const int c = c0 + j;
    const float mu = colsum[c] * invN;
    const float var = colsumsq[c] * invN - mu * mu;
    const float rs = rsqrtf(var + EPS_BN);
    const float tv = (out[j] - mu) * rs * gamma[c] + beta[c];
    out[j] = fmaxf(tv, 0.f);
  }
  float4 o4 = {out[0], out[1], out[2], out[3]};
  *(float4*)(h + (size_t)i * 4) = o4;
}

extern "C" void kernel_launch(void* const* d_in, const int* in_sizes, int n_in,
                              void* d_out, int out_size, void* d_ws, size_t ws_size,
                              hipStream_t stream) {
  const float* inputs  = (const float*)d_in[0];
  const int*   index   = (const int*)d_in[1];
  const float* deg_emb = (const float*)d_in[2];
  const float* W       = (const float*)d_in[3];
  const float* gamma   = (const float*)d_in[4];
  const float* beta    = (const float*)d_in[5];
  const int E = in_sizes[1];

  char* ws = (char*)d_ws;
  size_t o = 0;
  int* counts = (int*)(ws + o);       o += (size_t)NNODES * 4;
  float* colsum = (float*)(ws + o);   o += 128 * 4;
  float* colsumsq = (float*)(ws + o); o += 128 * 4;
  const size_t zero_bytes = o;        // counts + colsum + colsumsq zeroed together
  o = (o + 255) & ~(size_t)255;
  int* offsets = (int*)(ws + o);      o += (size_t)NNODES * 4;
  o = (o + 255) & ~(size_t)255;
  int* cursor = (int*)(ws + o);       o += (size_t)NNODES * 4;
  o = (o + 255) & ~(size_t)255;
  int* blocksums = (int*)(ws + o);    o += 256 * 4;
  o = (o + 255) & ~(size_t)255;
  int* sorted = (int*)(ws + o);       o += (size_t)E * 4;
  o = (o + 255) & ~(size_t)255;
  unsigned short* Wt = (unsigned short*)(ws + o); o += (size_t)OUTD * K5 * 2;
  o = (o + 255) & ~(size_t)255;
  unsigned short* x = (unsigned short*)(ws + o);  o += (size_t)MPAD * K5 * 2;

  float* h = (float*)d_out;

  hipMemsetAsync(counts, 0, zero_bytes, stream);
  hist_k<<<(E + 255) / 256, 256, 0, stream>>>(index, counts, E);
  const int NB = (NNODES + 255) / 256;
  scan1_k<<<NB, 256, 0, stream>>>(counts, offsets, blocksums, NNODES);
  scan2_k<<<1, 256, 0, stream>>>(blocksums, NB);
  scan3_k<<<NB, 256, 0, stream>>>(offsets, blocksums, cursor, NNODES);
  scatter_k<<<(E + 255) / 256, 256, 0, stream>>>(index, cursor, sorted, E);
  convW_k<<<(OUTD * K5 + 255) / 256, 256, 0, stream>>>(W, Wt);
  agg_k<<<MPAD / 4, 256, 0, stream>>>(inputs, sorted, offsets, counts, deg_emb, x);
  gemm_k<<<MPAD / 64, 256, 0, stream>>>(x, Wt, h, colsum, colsumsq);
  norm_k<<<(NNODES * OUTD / 4 + 255) / 256, 256, 0, stream>>>(h, colsum, colsumsq, gamma, beta);
}